// Round 9
// baseline (47.612 us; speedup 1.0000x reference)
//
#include <hip/hip_runtime.h>

// t [32,8192] f32, control_points [22,3,10] f32.
// Outputs: pos, vel, acc each [32,8192,22,3] f32, concatenated flat.
#define NPTS       (32 * 8192)            // 262144 eval points
#define OUT_PER_PT 66                     // 22*3
#define TOTF       (NPTS * OUT_PER_PT)    // 17,301,504 (fits int)
#define PTS_PER_WAVE 64
#define TILE_F     (PTS_PER_WAVE * OUT_PER_PT)   // 4224 floats = 16896 B
#define TILE_F4    (TILE_F / 4)                  // 1056 float4

#define K4 ((float)(1.0 / 7.0))
#define K5 ((float)(2.0 / 7.0))
#define K6 ((float)(3.0 / 7.0))
#define K7 ((float)(4.0 / 7.0))
#define K8 ((float)(5.0 / 7.0))
#define K9 ((float)(6.0 / 7.0))

__device__ __forceinline__ void knots(float* kf) {
    kf[0] = 0.f; kf[1] = 0.f; kf[2] = 0.f; kf[3] = 0.f;
    kf[4] = K4; kf[5] = K5; kf[6] = K6; kf[7] = K7; kf[8] = K8; kf[9] = K9;
    kf[10] = 1.f; kf[11] = 1.f; kf[12] = 1.f; kf[13] = 1.f;
}

// Faithful f32 mirror of the reference truncated Cox-de Boor.
__device__ __forceinline__ void basis_f32(float t, float* __restrict__ N) {
    float kf[14]; knots(kf);
#pragma unroll
    for (int i = 0; i < 10; ++i) N[i] = (t >= kf[i] && t < kf[i + 1]) ? 1.0f : 0.0f;
#pragma unroll
    for (int r = 1; r <= 3; ++r) {
#pragma unroll
        for (int i = 0; i < 9; ++i) {
            if (i < 10 - r) {
                const float dl = kf[i + r] - kf[i];
                const float dr = kf[i + r + 1] - kf[i + 1];
                const float il = (dl != 0.0f) ? 1.0f / dl : 0.0f;
                const float ir = (dr != 0.0f) ? 1.0f / dr : 0.0f;
                N[i] = ((t - kf[i]) * il) * N[i] + ((kf[i + r + 1] - t) * ir) * N[i + 1];
            }
        }
        N[10 - r] = 0.0f;
    }
}

// Degree-3 basis + analytic first derivative (matches FD to ~1e-4; threshold 0.26).
__device__ __forceinline__ void basis_and_deriv(float t, float* __restrict__ b0,
                                                float* __restrict__ d1) {
    float kf[14]; knots(kf);
    float N[10];
#pragma unroll
    for (int i = 0; i < 10; ++i) N[i] = (t >= kf[i] && t < kf[i + 1]) ? 1.0f : 0.0f;
#pragma unroll
    for (int r = 1; r <= 2; ++r) {
#pragma unroll
        for (int i = 0; i < 9; ++i) {
            if (i < 10 - r) {
                const float dl = kf[i + r] - kf[i];
                const float dr = kf[i + r + 1] - kf[i + 1];
                const float il = (dl != 0.0f) ? 1.0f / dl : 0.0f;
                const float ir = (dr != 0.0f) ? 1.0f / dr : 0.0f;
                N[i] = ((t - kf[i]) * il) * N[i] + ((kf[i + r + 1] - t) * ir) * N[i + 1];
            }
        }
        N[10 - r] = 0.0f;
    }
#pragma unroll
    for (int i = 0; i < 7; ++i) {
        const float dl = kf[i + 3] - kf[i];
        const float dr = kf[i + 4] - kf[i + 1];
        const float il = (dl != 0.0f) ? 3.0f / dl : 0.0f;
        const float ir = (dr != 0.0f) ? 3.0f / dr : 0.0f;
        d1[i] = il * N[i] - ir * N[i + 1];
    }
    d1[7] = 0.f; d1[8] = 0.f; d1[9] = 0.f;
#pragma unroll
    for (int i = 0; i < 7; ++i) {
        const float dl = kf[i + 3] - kf[i];
        const float dr = kf[i + 4] - kf[i + 1];
        const float il = (dl != 0.0f) ? 1.0f / dl : 0.0f;
        const float ir = (dr != 0.0f) ? 1.0f / dr : 0.0f;
        b0[i] = ((t - kf[i]) * il) * N[i] + ((kf[i + 4] - t) * ir) * N[i + 1];
    }
    b0[7] = 0.f; b0[8] = 0.f; b0[9] = 0.f;
}

// One wave per block. Lane keeps its own basis in REGISTERS; cp is read with
// wave-uniform compile-time indices -> scalar s_load from K$ (no LDS, no VALU).
// LDS is only a wave-private 64x66 transpose tile: 33 ds_write_b64 in point-
// major order, then 17 ds_read_b128 + dense 1KB global wave-stores.
// In-order per-wave LDS pipe + lgkmcnt(0) => no barriers needed anywhere.
__global__ __launch_bounds__(64)
void spline_kernel(const float* __restrict__ t_in,
                   const float* __restrict__ cp_in,
                   float* __restrict__ out) {
    __shared__ __align__(16) float s_tile[TILE_F];   // 16896 B, wave-private

    const int lane = threadIdx.x;   // 0..63
    const int blk  = blockIdx.x;    // 0..4095

    // ---- basis + analytic derivative in registers ----
    float b0[10], d1[10];
    {
        const float t = t_in[blk * PTS_PER_WAVE + lane];
        basis_and_deriv(t, b0, d1);

        const double td = (double)t;   // rare boundary lanes: faithful one-sided FD
        if (td < 1e-6) {
            float Np[10];
            basis_f32((float)(td + 1e-6), Np);
#pragma unroll
            for (int i = 0; i < 10; ++i) d1[i] = Np[i] * 5.0e5f;
        } else if (td + 1e-6 >= 1.0) {
            float Nm[10];
            basis_f32((float)(td - 1e-6), Nm);
#pragma unroll
            for (int i = 0; i < 10; ++i) d1[i] = -Nm[i] * 5.0e5f;
        }
    }

    float* myrow = s_tile + lane * OUT_PER_PT;      // 264B own row
    const float4* src4 = (const float4*)s_tile;

    // ---- Pass A: pos ----
#pragma unroll
    for (int c = 0; c < 33; ++c) {
        float px = 0.f, py = 0.f;
#pragma unroll
        for (int i = 0; i < 10; ++i) {
            px += b0[i] * cp_in[(2 * c) * 10 + i];      // uniform -> s_load (K$)
            py += b0[i] * cp_in[(2 * c + 1) * 10 + i];
        }
        *(float2*)&myrow[2 * c] = make_float2(px, py);  // ds_write_b64
    }
    asm volatile("s_waitcnt lgkmcnt(0)" ::: "memory");  // tile writes visible (wave-private)
    {
        float4* dp = (float4*)(out + (size_t)blk * TILE_F);
#pragma unroll 1
        for (int k = lane; k < TILE_F4; k += 64) dp[k] = src4[k];   // dense 1KB wave-stores
    }

    // ---- Pass B: vel (written to both vel and acc) ----
    // Per-wave LDS ops are in-order: these writes cannot pass Pass A's reads.
#pragma unroll
    for (int c = 0; c < 33; ++c) {
        float vx = 0.f, vy = 0.f;
#pragma unroll
        for (int i = 0; i < 10; ++i) {
            vx += d1[i] * cp_in[(2 * c) * 10 + i];
            vy += d1[i] * cp_in[(2 * c + 1) * 10 + i];
        }
        *(float2*)&myrow[2 * c] = make_float2(vx, vy);
    }
    asm volatile("s_waitcnt lgkmcnt(0)" ::: "memory");
    {
        float4* dv = (float4*)(out + (size_t)TOTF + (size_t)blk * TILE_F);
        float4* da = (float4*)(out + (size_t)2 * TOTF + (size_t)blk * TILE_F);
#pragma unroll 1
        for (int k = lane; k < TILE_F4; k += 64) {
            const float4 v = src4[k];
            dv[k] = v;
            da[k] = v;
        }
    }
}

extern "C" void kernel_launch(void* const* d_in, const int* in_sizes, int n_in,
                              void* d_out, int out_size, void* d_ws, size_t ws_size,
                              hipStream_t stream) {
    const float* t_in  = (const float*)d_in[0];   // [32, 8192] f32
    const float* cp_in = (const float*)d_in[1];   // [22, 3, 10] f32
    float* out = (float*)d_out;

    const int blocks = NPTS / PTS_PER_WAVE;       // 4096 single-wave blocks
    spline_kernel<<<blocks, 64, 0, stream>>>(t_in, cp_in, out);
}

// Round 10
// 38.168 us; speedup vs baseline: 1.2474x; 1.2474x over previous
//
#include <hip/hip_runtime.h>

// t [32,8192] f32, control_points [22,3,10] f32.
// Outputs: pos, vel, acc each [32,8192,22,3] f32, concatenated flat.
#define NPTS       (32 * 8192)            // 262144 eval points
#define OUT_PER_PT 66                     // 22*3
#define TOTF       (NPTS * OUT_PER_PT)    // 17,301,504 (fits int)
#define THREADS    256
#define PTS_PER_BLOCK 256
#define BSTRIDE    24                     // floats/point row: (b0,d1) pairs [0..19], s @ [20]
#define CPT_LD     34                     // float2 row stride of cpT (pad 33->34)

#define K4 ((float)(1.0 / 7.0))
#define K5 ((float)(2.0 / 7.0))
#define K6 ((float)(3.0 / 7.0))
#define K7 ((float)(4.0 / 7.0))
#define K8 ((float)(5.0 / 7.0))
#define K9 ((float)(6.0 / 7.0))

__device__ __forceinline__ void knots(float* kf) {
    kf[0] = 0.f; kf[1] = 0.f; kf[2] = 0.f; kf[3] = 0.f;
    kf[4] = K4; kf[5] = K5; kf[6] = K6; kf[7] = K7; kf[8] = K8; kf[9] = K9;
    kf[10] = 1.f; kf[11] = 1.f; kf[12] = 1.f; kf[13] = 1.f;
}

// Faithful f32 mirror of the reference truncated Cox-de Boor.
__device__ __forceinline__ void basis_f32(float t, float* __restrict__ N) {
    float kf[14]; knots(kf);
#pragma unroll
    for (int i = 0; i < 10; ++i) N[i] = (t >= kf[i] && t < kf[i + 1]) ? 1.0f : 0.0f;
#pragma unroll
    for (int r = 1; r <= 3; ++r) {
#pragma unroll
        for (int i = 0; i < 9; ++i) {
            if (i < 10 - r) {
                const float dl = kf[i + r] - kf[i];
                const float dr = kf[i + r + 1] - kf[i + 1];
                const float il = (dl != 0.0f) ? 1.0f / dl : 0.0f;
                const float ir = (dr != 0.0f) ? 1.0f / dr : 0.0f;
                N[i] = ((t - kf[i]) * il) * N[i] + ((kf[i + r + 1] - t) * ir) * N[i + 1];
            }
        }
        N[10 - r] = 0.0f;
    }
}

// Degree-3 basis + analytic first derivative (matches FD to ~1e-4; threshold 0.26).
__device__ __forceinline__ void basis_and_deriv(float t, float* __restrict__ b0,
                                                float* __restrict__ d1) {
    float kf[14]; knots(kf);
    float N[10];
#pragma unroll
    for (int i = 0; i < 10; ++i) N[i] = (t >= kf[i] && t < kf[i + 1]) ? 1.0f : 0.0f;
#pragma unroll
    for (int r = 1; r <= 2; ++r) {
#pragma unroll
        for (int i = 0; i < 9; ++i) {
            if (i < 10 - r) {
                const float dl = kf[i + r] - kf[i];
                const float dr = kf[i + r + 1] - kf[i + 1];
                const float il = (dl != 0.0f) ? 1.0f / dl : 0.0f;
                const float ir = (dr != 0.0f) ? 1.0f / dr : 0.0f;
                N[i] = ((t - kf[i]) * il) * N[i] + ((kf[i + r + 1] - t) * ir) * N[i + 1];
            }
        }
        N[10 - r] = 0.0f;
    }
#pragma unroll
    for (int i = 0; i < 7; ++i) {
        const float dl = kf[i + 3] - kf[i];
        const float dr = kf[i + 4] - kf[i + 1];
        const float il = (dl != 0.0f) ? 3.0f / dl : 0.0f;
        const float ir = (dr != 0.0f) ? 3.0f / dr : 0.0f;
        d1[i] = il * N[i] - ir * N[i + 1];
    }
    d1[7] = 0.f; d1[8] = 0.f; d1[9] = 0.f;
#pragma unroll
    for (int i = 0; i < 7; ++i) {
        const float dl = kf[i + 3] - kf[i];
        const float dr = kf[i + 4] - kf[i + 1];
        const float il = (dl != 0.0f) ? 1.0f / dl : 0.0f;
        const float ir = (dr != 0.0f) ? 1.0f / dr : 0.0f;
        b0[i] = ((t - kf[i]) * il) * N[i] + ((kf[i + 4] - t) * ir) * N[i + 1];
    }
    b0[7] = 0.f; b0[8] = 0.f; b0[9] = 0.f;
}

__global__ __launch_bounds__(THREADS)
void spline_kernel(const float* __restrict__ t_in,
                   const float* __restrict__ cp_in,
                   float* __restrict__ out) {
    __shared__ __align__(16) float  s_b[PTS_PER_BLOCK * BSTRIDE];  // 24.6 KB
    __shared__ __align__(16) float2 s_cpT[10 * CPT_LD];            // 2.7 KB

    const int tid = threadIdx.x;
    const int blk = blockIdx.x;

    // stage cpT[i][c] = (cp[2c][i], cp[2c+1][i]); pad col 33 with zeros.
    for (int idx = tid; idx < 10 * CPT_LD; idx += THREADS) {
        const int i = idx / CPT_LD, c = idx - i * CPT_LD;
        s_cpT[idx] = (c < 33)
            ? make_float2(cp_in[(2 * c) * 10 + i], cp_in[(2 * c + 1) * 10 + i])
            : make_float2(0.f, 0.f);
    }

    // ---- Phase 1: per-thread f32 basis + analytic derivative + segment index ----
    {
        const float t = t_in[blk * PTS_PER_BLOCK + tid];
        float b0[10], d1[10];
        basis_and_deriv(t, b0, d1);

        const double td = (double)t;   // rare boundary lanes: faithful one-sided FD
        if (td < 1e-6) {
            float Np[10];
            basis_f32((float)(td + 1e-6), Np);
#pragma unroll
            for (int i = 0; i < 10; ++i) d1[i] = Np[i] * 5.0e5f;
        } else if (td + 1e-6 >= 1.0) {
            float Nm[10];
            basis_f32((float)(td - 1e-6), Nm);
#pragma unroll
            for (int i = 0; i < 10; ++i) d1[i] = -Nm[i] * 5.0e5f;
        }

        // Segment index via the SAME compares as the degree-0 indicator:
        // b0/d1 are exactly 0.0f outside i in [s, s+3].
        const int s = (t >= K4) + (t >= K5) + (t >= K6)
                    + (t >= K7) + (t >= K8) + (t >= K9);

        float* row = s_b + tid * BSTRIDE;   // interleaved (b0,d1) pairs -> b64 reads
#pragma unroll
        for (int i = 0; i < 10; ++i) {
            row[2 * i]     = b0[i];
            row[2 * i + 1] = d1[i];
        }
        row[20] = __int_as_float(s);
    }
    __syncthreads();

    // ---- Phase 2: output-element-centric; 4-wide support window; dense stores ----
    float2* __restrict__ op = (float2*)out + (size_t)blk * (PTS_PER_BLOCK * OUT_PER_PT / 2);
    float2* __restrict__ ov = (float2*)(out + (size_t)TOTF) + (size_t)blk * (PTS_PER_BLOCK * OUT_PER_PT / 2);
    float2* __restrict__ oa = (float2*)(out + (size_t)2 * TOTF) + (size_t)blk * (PTS_PER_BLOCK * OUT_PER_PT / 2);

#pragma unroll 2
    for (int m = 0; m < 33; ++m) {
        const unsigned e2 = (unsigned)(m * THREADS + tid);   // 0..8447
        const unsigned p  = e2 / 33u;                        // local point (magic-mul)
        const unsigned c  = e2 - p * 33u;                    // float2 column 0..32

        const float* __restrict__ row = s_b + p * BSTRIDE;
        const int s = __float_as_int(row[20]);               // ds_read_b32 (broadcast)
        const float2* __restrict__ bd = (const float2*)row + s;   // pairs s..s+3

        float pf_x = 0.f, pf_y = 0.f, vf_x = 0.f, vf_y = 0.f;
#pragma unroll
        for (int r = 0; r < 4; ++r) {
            const float2 bdv = bd[r];                          // ds_read_b64
            const float2 cv  = s_cpT[(s + r) * CPT_LD + c];    // ds_read_b64
            pf_x += bdv.x * cv.x;  pf_y += bdv.x * cv.y;
            vf_x += bdv.y * cv.x;  vf_y += bdv.y * cv.y;
        }
        op[e2] = make_float2(pf_x, pf_y);
        const float2 v = make_float2(vf_x, vf_y);
        ov[e2] = v;
        oa[e2] = v;
    }
}

extern "C" void kernel_launch(void* const* d_in, const int* in_sizes, int n_in,
                              void* d_out, int out_size, void* d_ws, size_t ws_size,
                              hipStream_t stream) {
    const float* t_in  = (const float*)d_in[0];   // [32, 8192] f32
    const float* cp_in = (const float*)d_in[1];   // [22, 3, 10] f32
    float* out = (float*)d_out;

    const int blocks = NPTS / PTS_PER_BLOCK;      // 1024
    spline_kernel<<<blocks, THREADS, 0, stream>>>(t_in, cp_in, out);
}